// Round 1
// baseline (1433.415 us; speedup 1.0000x reference)
//
#include <hip/hip_runtime.h>
#include <math.h>

#define CDIM 256
#define RBFD 16
#define NATOMS 10000

__device__ __forceinline__ float dot4f(float4 a, float4 b) {
  return a.x * b.x + a.y * b.y + a.z * b.z + a.w * b.w;
}

// ---------------------------------------------------------------------------
// Edge phase: one wave per edge. Lane l owns channels 4l..4l+3.
// filter[c] = b_rbf[c] + sum_r rbf[e][r] * w_rbf[c][r]; msg = filter * x[e][c]
// atomicAdd into acc[atom][c].
// w_rbf rows for this lane are hoisted to registers (grid-stride amortizes).
// ---------------------------------------------------------------------------
__global__ __launch_bounds__(256, 4) void edge_kernel(
    const float* __restrict__ x, const float* __restrict__ rbf,
    const int* __restrict__ eidx, const float* __restrict__ w_rbf,
    const float* __restrict__ b_rbf, float* __restrict__ acc, int E) {
  const int lane = threadIdx.x & 63;
  const int wid = (blockIdx.x * blockDim.x + threadIdx.x) >> 6;
  const int nwaves = (gridDim.x * blockDim.x) >> 6;
  const int c0 = lane * 4;

  // Hoist this lane's 4 rows of w_rbf (4x16 floats) + bias into registers.
  float4 wv[4][4];
  const float4 bb = *(const float4*)(b_rbf + c0);
#pragma unroll
  for (int j = 0; j < 4; ++j) {
    const float4* wr = (const float4*)(w_rbf + (size_t)(c0 + j) * RBFD);
    wv[j][0] = wr[0];
    wv[j][1] = wr[1];
    wv[j][2] = wr[2];
    wv[j][3] = wr[3];
  }

  for (int e = wid; e < E; e += nwaves) {
    const int a = eidx[e];  // wave-uniform
    const float4* rp = (const float4*)(rbf + (size_t)e * RBFD);
    const float4 r0 = rp[0], r1 = rp[1], r2 = rp[2], r3 = rp[3];
    const float4 xx = *(const float4*)(x + (size_t)e * CDIM + c0);

    float4 f;
    f.x = bb.x + dot4f(wv[0][0], r0) + dot4f(wv[0][1], r1) +
          dot4f(wv[0][2], r2) + dot4f(wv[0][3], r3);
    f.y = bb.y + dot4f(wv[1][0], r0) + dot4f(wv[1][1], r1) +
          dot4f(wv[1][2], r2) + dot4f(wv[1][3], r3);
    f.z = bb.z + dot4f(wv[2][0], r0) + dot4f(wv[2][1], r1) +
          dot4f(wv[2][2], r2) + dot4f(wv[2][3], r3);
    f.w = bb.w + dot4f(wv[3][0], r0) + dot4f(wv[3][1], r1) +
          dot4f(wv[3][2], r2) + dot4f(wv[3][3], r3);

    float* dst = acc + (size_t)a * CDIM + c0;
    atomicAdd(dst + 0, f.x * xx.x);
    atomicAdd(dst + 1, f.y * xx.y);
    atomicAdd(dst + 2, f.z * xx.z);
    atomicAdd(dst + 3, f.w * xx.w);
  }
}

// ---------------------------------------------------------------------------
// Transpose w1, w2 (256x256) into k-major layout so MLP kernel can stage
// W chunks with coalesced loads and conflict-free ds_read_b128.
// ---------------------------------------------------------------------------
__global__ void transpose_kernel(const float* __restrict__ w1,
                                 const float* __restrict__ w2,
                                 float* __restrict__ w1T,
                                 float* __restrict__ w2T) {
  __shared__ float tile[32][33];
  const float* src = blockIdx.z ? w2 : w1;
  float* dst = blockIdx.z ? w2T : w1T;
  const int bx = blockIdx.x * 32;  // column range in src (k)
  const int by = blockIdx.y * 32;  // row range in src (c_out)
  const int tx = threadIdx.x, ty = threadIdx.y;  // (32, 8)
#pragma unroll
  for (int i = 0; i < 32; i += 8)
    tile[ty + i][tx] = src[(size_t)(by + ty + i) * CDIM + bx + tx];
  __syncthreads();
#pragma unroll
  for (int i = 0; i < 32; i += 8)
    dst[(size_t)(bx + ty + i) * CDIM + by + tx] = tile[tx][ty + i];
}

// ---------------------------------------------------------------------------
// Fused per-atom MLP: silu(h@w1T+b1) -> silu(@w2T+b2) -> @w3T+b3 (scalar).
// Block = 256 threads, 32 atoms. Thread tile = 4 atoms x 8 channels.
// H tile [32][256] (32KB) + W chunk [32][256] (32KB) in LDS.
// ---------------------------------------------------------------------------
__global__ __launch_bounds__(256, 2) void mlp_kernel(
    const float* __restrict__ hin, const float* __restrict__ w1T,
    const float* __restrict__ b1, const float* __restrict__ w2T,
    const float* __restrict__ b2, const float* __restrict__ w3,
    const float* __restrict__ b3, float* __restrict__ out, int natoms) {
  __shared__ float H[32 * 256];   // [atom][k]
  __shared__ float WK[32 * 256];  // [k_local][c_out]; reused as reduce buffer
  const int tid = threadIdx.x;
  const int tc = tid & 31;   // channel group 0..31 -> channels 8*tc..8*tc+7
  const int ta = tid >> 5;   // atom group 0..7 -> atoms 4*ta..4*ta+3
  const int a0 = blockIdx.x * 32;
  const int c0 = tc * 8;

  // Stage H (zero-pad invalid atoms in last block).
  {
    const float4* src = (const float4*)hin + (size_t)a0 * 64;
    float4* Hv = (float4*)H;
#pragma unroll
    for (int i = 0; i < 8; ++i) {
      const int idx = tid + i * 256;  // 0..2047
      const int ga = a0 + (idx >> 6);
      Hv[idx] = (ga < natoms) ? src[idx] : make_float4(0.f, 0.f, 0.f, 0.f);
    }
  }

  float s[4][8];  // post-silu activations of current layer

#pragma unroll 1
  for (int layer = 0; layer < 2; ++layer) {
    const float* wT = (layer == 0) ? w1T : w2T;
    const float* bias = (layer == 0) ? b1 : b2;
    float r[4][8];
    const float4 bA = *(const float4*)(bias + c0);
    const float4 bB = *(const float4*)(bias + c0 + 4);
#pragma unroll
    for (int a = 0; a < 4; ++a) {
      r[a][0] = bA.x; r[a][1] = bA.y; r[a][2] = bA.z; r[a][3] = bA.w;
      r[a][4] = bB.x; r[a][5] = bB.y; r[a][6] = bB.z; r[a][7] = bB.w;
    }

    for (int k0 = 0; k0 < 256; k0 += 32) {
      __syncthreads();  // previous chunk (or H-stage/h1-write) fully consumed
      // Stage WK = wT rows k0..k0+31 (contiguous, coalesced).
      {
        const float4* wsrc = (const float4*)(wT + (size_t)k0 * CDIM);
        float4* WKv = (float4*)WK;
#pragma unroll
        for (int i = 0; i < 8; ++i) WKv[tid + i * 256] = wsrc[tid + i * 256];
      }
      __syncthreads();

#pragma unroll
      for (int kk = 0; kk < 32; kk += 4) {
        float4 ha[4];
#pragma unroll
        for (int a = 0; a < 4; ++a)
          ha[a] = *(const float4*)&H[(ta * 4 + a) * 256 + k0 + kk];
#pragma unroll
        for (int u = 0; u < 4; ++u) {
          const float4 w0 = *(const float4*)&WK[(kk + u) * 256 + c0];
          const float4 w1v = *(const float4*)&WK[(kk + u) * 256 + c0 + 4];
#pragma unroll
          for (int a = 0; a < 4; ++a) {
            const float hv = (u == 0) ? ha[a].x
                           : (u == 1) ? ha[a].y
                           : (u == 2) ? ha[a].z : ha[a].w;
            r[a][0] += hv * w0.x;  r[a][1] += hv * w0.y;
            r[a][2] += hv * w0.z;  r[a][3] += hv * w0.w;
            r[a][4] += hv * w1v.x; r[a][5] += hv * w1v.y;
            r[a][6] += hv * w1v.z; r[a][7] += hv * w1v.w;
          }
        }
      }
    }

    // SiLU
#pragma unroll
    for (int a = 0; a < 4; ++a)
#pragma unroll
      for (int j = 0; j < 8; ++j) {
        const float v = r[a][j];
        s[a][j] = v / (1.0f + __expf(-v));
      }

    if (layer == 0) {
      __syncthreads();  // all H reads of layer 1 done
#pragma unroll
      for (int a = 0; a < 4; ++a) {
        *(float4*)&H[(ta * 4 + a) * 256 + c0] =
            make_float4(s[a][0], s[a][1], s[a][2], s[a][3]);
        *(float4*)&H[(ta * 4 + a) * 256 + c0 + 4] =
            make_float4(s[a][4], s[a][5], s[a][6], s[a][7]);
      }
      // next chunk's leading __syncthreads() orders these writes vs reads
    }
  }

  // Layer 3: per-atom dot with w3, reduce across the 32 channel groups.
  const float4 w3a = *(const float4*)(w3 + c0);
  const float4 w3b = *(const float4*)(w3 + c0 + 4);
  float part[4];
#pragma unroll
  for (int a = 0; a < 4; ++a) {
    part[a] = s[a][0] * w3a.x + s[a][1] * w3a.y + s[a][2] * w3a.z +
              s[a][3] * w3a.w + s[a][4] * w3b.x + s[a][5] * w3b.y +
              s[a][6] * w3b.z + s[a][7] * w3b.w;
  }
  __syncthreads();  // WK reads done; reuse as reduce buffer [32][33]
  float* red = WK;
#pragma unroll
  for (int a = 0; a < 4; ++a) red[(ta * 4 + a) * 33 + tc] = part[a];
  __syncthreads();
  if (tid < 32) {
    float sum = 0.f;
#pragma unroll
    for (int j = 0; j < 32; ++j) sum += red[tid * 33 + j];
    const int ga = a0 + tid;
    if (ga < natoms) out[ga] = sum + b3[0];
  }
}

extern "C" void kernel_launch(void* const* d_in, const int* in_sizes, int n_in,
                              void* d_out, int out_size, void* d_ws,
                              size_t ws_size, hipStream_t stream) {
  const float* x = (const float*)d_in[0];
  const float* rbf = (const float*)d_in[1];
  // d_in[2] = num_atoms scalar (device); problem-fixed at 10000.
  const int* eidx = (const int*)d_in[3];
  const float* w_rbf = (const float*)d_in[4];
  const float* b_rbf = (const float*)d_in[5];
  const float* w1 = (const float*)d_in[6];
  const float* b1 = (const float*)d_in[7];
  const float* w2 = (const float*)d_in[8];
  const float* b2 = (const float*)d_in[9];
  const float* w3 = (const float*)d_in[10];
  const float* b3 = (const float*)d_in[11];
  float* out = (float*)d_out;
  const int E = in_sizes[0] / CDIM;

  // Workspace layout: acc [10000][256] f32, then w1T, w2T (256x256 each).
  float* acc = (float*)d_ws;
  float* w1T = (float*)((char*)d_ws + (size_t)NATOMS * CDIM * sizeof(float));
  float* w2T = w1T + CDIM * CDIM;

  hipMemsetAsync(acc, 0, (size_t)NATOMS * CDIM * sizeof(float), stream);
  transpose_kernel<<<dim3(8, 8, 2), dim3(32, 8), 0, stream>>>(w1, w2, w1T,
                                                              w2T);
  edge_kernel<<<2048, 256, 0, stream>>>(x, rbf, eidx, w_rbf, b_rbf, acc, E);
  mlp_kernel<<<(NATOMS + 31) / 32, 256, 0, stream>>>(acc, w1T, b1, w2T, b2, w3,
                                                     b3, out, NATOMS);
}

// Round 2
// 662.270 us; speedup vs baseline: 2.1644x; 2.1644x over previous
//
#include <hip/hip_runtime.h>
#include <math.h>

#define CDIM 256
#define RBFD 16
#define NATOMS 10000

__device__ __forceinline__ float dot4f(float4 a, float4 b) {
  return a.x * b.x + a.y * b.y + a.z * b.z + a.w * b.w;
}

// ---------------------------------------------------------------------------
// CSR build: histogram -> single-block exclusive scan -> scatter edge ids.
// ---------------------------------------------------------------------------
__global__ void hist_kernel(const int* __restrict__ eidx, int* __restrict__ counts,
                            int E) {
  const int i = blockIdx.x * blockDim.x + threadIdx.x;
  if (i < E) atomicAdd(&counts[eidx[i]], 1);
}

__global__ void scan_kernel(const int* __restrict__ counts,
                            int* __restrict__ offsets, int* __restrict__ cursor) {
  __shared__ int part[256];
  const int t = threadIdx.x;
  const int CH = (NATOMS + 255) / 256;  // 40
  const int base = t * CH;
  const int n = min(CH, max(0, NATOMS - base));
  int s = 0;
  for (int j = 0; j < n; ++j) s += counts[base + j];
  part[t] = s;
  __syncthreads();
  for (int off = 1; off < 256; off <<= 1) {
    int v = 0;
    if (t >= off) v = part[t - off];
    __syncthreads();
    part[t] += v;
    __syncthreads();
  }
  int run = part[t] - s;  // exclusive start for this chunk
  for (int j = 0; j < n; ++j) {
    offsets[base + j] = run;
    cursor[base + j] = run;
    run += counts[base + j];
  }
  if (t == 255) offsets[NATOMS] = part[255];
}

__global__ void scatter_kernel(const int* __restrict__ eidx,
                               int* __restrict__ cursor, int* __restrict__ elist,
                               int E) {
  const int i = blockIdx.x * blockDim.x + threadIdx.x;
  if (i < E) {
    const int a = eidx[i];
    const int pos = atomicAdd(&cursor[a], 1);
    elist[pos] = i;
  }
}

// ---------------------------------------------------------------------------
// Gather phase: one wave per atom. Lane l owns channels 4l..4l+3.
// acc[a][c] = sum_{e in bucket(a)} (b_rbf[c] + rbf[e]·w_rbf[c]) * x[e][c]
// No atomics: one float4 store per lane at the end.
// ---------------------------------------------------------------------------
__global__ __launch_bounds__(256, 4) void gather_kernel(
    const float* __restrict__ x, const float* __restrict__ rbf,
    const int* __restrict__ elist, const int* __restrict__ offsets,
    const float* __restrict__ w_rbf, const float* __restrict__ b_rbf,
    float* __restrict__ acc) {
  const int lane = threadIdx.x & 63;
  const int atom = (blockIdx.x * blockDim.x + threadIdx.x) >> 6;
  if (atom >= NATOMS) return;
  const int c0 = lane * 4;

  // Hoist this lane's 4 rows of w_rbf (4x16 floats) + bias into registers.
  float4 wv[4][4];
  const float4 bb = *(const float4*)(b_rbf + c0);
#pragma unroll
  for (int j = 0; j < 4; ++j) {
    const float4* wr = (const float4*)(w_rbf + (size_t)(c0 + j) * RBFD);
    wv[j][0] = wr[0];
    wv[j][1] = wr[1];
    wv[j][2] = wr[2];
    wv[j][3] = wr[3];
  }

  const int start = offsets[atom];
  const int end = offsets[atom + 1];
  float4 sum = make_float4(0.f, 0.f, 0.f, 0.f);

  int e = (start < end) ? elist[start] : 0;  // prefetch one ahead
  for (int i = start; i < end; ++i) {
    const int e_next = (i + 1 < end) ? elist[i + 1] : 0;
    const float4* rp = (const float4*)(rbf + (size_t)e * RBFD);
    const float4 r0 = rp[0], r1 = rp[1], r2 = rp[2], r3 = rp[3];
    const float4 xx = *(const float4*)(x + (size_t)e * CDIM + c0);

    float4 f;
    f.x = bb.x + dot4f(wv[0][0], r0) + dot4f(wv[0][1], r1) +
          dot4f(wv[0][2], r2) + dot4f(wv[0][3], r3);
    f.y = bb.y + dot4f(wv[1][0], r0) + dot4f(wv[1][1], r1) +
          dot4f(wv[1][2], r2) + dot4f(wv[1][3], r3);
    f.z = bb.z + dot4f(wv[2][0], r0) + dot4f(wv[2][1], r1) +
          dot4f(wv[2][2], r2) + dot4f(wv[2][3], r3);
    f.w = bb.w + dot4f(wv[3][0], r0) + dot4f(wv[3][1], r1) +
          dot4f(wv[3][2], r2) + dot4f(wv[3][3], r3);

    sum.x += f.x * xx.x;
    sum.y += f.y * xx.y;
    sum.z += f.z * xx.z;
    sum.w += f.w * xx.w;
    e = e_next;
  }
  *(float4*)(acc + (size_t)atom * CDIM + c0) = sum;
}

// ---------------------------------------------------------------------------
// Transpose w1, w2 (256x256) into k-major layout.
// ---------------------------------------------------------------------------
__global__ void transpose_kernel(const float* __restrict__ w1,
                                 const float* __restrict__ w2,
                                 float* __restrict__ w1T,
                                 float* __restrict__ w2T) {
  __shared__ float tile[32][33];
  const float* src = blockIdx.z ? w2 : w1;
  float* dst = blockIdx.z ? w2T : w1T;
  const int bx = blockIdx.x * 32;
  const int by = blockIdx.y * 32;
  const int tx = threadIdx.x, ty = threadIdx.y;  // (32, 8)
#pragma unroll
  for (int i = 0; i < 32; i += 8)
    tile[ty + i][tx] = src[(size_t)(by + ty + i) * CDIM + bx + tx];
  __syncthreads();
#pragma unroll
  for (int i = 0; i < 32; i += 8)
    dst[(size_t)(bx + ty + i) * CDIM + by + tx] = tile[tx][ty + i];
}

// ---------------------------------------------------------------------------
// Fused per-atom MLP. Block = 256 threads, 32 atoms. Thread tile = 4 atoms x
// 8 channels, channels {4tc..4tc+3} and {128+4tc..128+4tc+3} so WK
// ds_read_b128s are lane-consecutive (conflict-free).
// ---------------------------------------------------------------------------
__global__ __launch_bounds__(256, 2) void mlp_kernel(
    const float* __restrict__ hin, const float* __restrict__ w1T,
    const float* __restrict__ b1, const float* __restrict__ w2T,
    const float* __restrict__ b2, const float* __restrict__ w3,
    const float* __restrict__ b3, float* __restrict__ out, int natoms) {
  __shared__ float H[32 * 256];   // [atom][k]
  __shared__ float WK[32 * 256];  // [k_local][c_out]; reused as reduce buffer
  const int tid = threadIdx.x;
  const int tc = tid & 31;
  const int ta = tid >> 5;
  const int a0 = blockIdx.x * 32;
  const int cA = tc * 4;        // channels cA..cA+3
  const int cB = 128 + tc * 4;  // channels cB..cB+3

  // Stage H (zero-pad invalid atoms in last block).
  {
    const float4* src = (const float4*)hin + (size_t)a0 * 64;
    float4* Hv = (float4*)H;
#pragma unroll
    for (int i = 0; i < 8; ++i) {
      const int idx = tid + i * 256;  // 0..2047
      const int ga = a0 + (idx >> 6);
      Hv[idx] = (ga < natoms) ? src[idx] : make_float4(0.f, 0.f, 0.f, 0.f);
    }
  }

  float s[4][8];  // post-silu activations of current layer

#pragma unroll 1
  for (int layer = 0; layer < 2; ++layer) {
    const float* wT = (layer == 0) ? w1T : w2T;
    const float* bias = (layer == 0) ? b1 : b2;
    float r[4][8];
    const float4 bA = *(const float4*)(bias + cA);
    const float4 bB = *(const float4*)(bias + cB);
#pragma unroll
    for (int a = 0; a < 4; ++a) {
      r[a][0] = bA.x; r[a][1] = bA.y; r[a][2] = bA.z; r[a][3] = bA.w;
      r[a][4] = bB.x; r[a][5] = bB.y; r[a][6] = bB.z; r[a][7] = bB.w;
    }

    for (int k0 = 0; k0 < 256; k0 += 32) {
      __syncthreads();  // previous chunk fully consumed
      {
        const float4* wsrc = (const float4*)(wT + (size_t)k0 * CDIM);
        float4* WKv = (float4*)WK;
#pragma unroll
        for (int i = 0; i < 8; ++i) WKv[tid + i * 256] = wsrc[tid + i * 256];
      }
      __syncthreads();

#pragma unroll
      for (int kk = 0; kk < 32; kk += 4) {
        float4 ha[4];
#pragma unroll
        for (int a = 0; a < 4; ++a)
          ha[a] = *(const float4*)&H[(ta * 4 + a) * 256 + k0 + kk];
#pragma unroll
        for (int u = 0; u < 4; ++u) {
          const float4 w0 = *(const float4*)&WK[(kk + u) * 256 + cA];
          const float4 w1v = *(const float4*)&WK[(kk + u) * 256 + cB];
#pragma unroll
          for (int a = 0; a < 4; ++a) {
            const float hv = (u == 0) ? ha[a].x
                           : (u == 1) ? ha[a].y
                           : (u == 2) ? ha[a].z : ha[a].w;
            r[a][0] += hv * w0.x;  r[a][1] += hv * w0.y;
            r[a][2] += hv * w0.z;  r[a][3] += hv * w0.w;
            r[a][4] += hv * w1v.x; r[a][5] += hv * w1v.y;
            r[a][6] += hv * w1v.z; r[a][7] += hv * w1v.w;
          }
        }
      }
    }

    // SiLU
#pragma unroll
    for (int a = 0; a < 4; ++a)
#pragma unroll
      for (int j = 0; j < 8; ++j) {
        const float v = r[a][j];
        s[a][j] = v / (1.0f + __expf(-v));
      }

    if (layer == 0) {
      __syncthreads();  // all H reads of layer 1 done
#pragma unroll
      for (int a = 0; a < 4; ++a) {
        *(float4*)&H[(ta * 4 + a) * 256 + cA] =
            make_float4(s[a][0], s[a][1], s[a][2], s[a][3]);
        *(float4*)&H[(ta * 4 + a) * 256 + cB] =
            make_float4(s[a][4], s[a][5], s[a][6], s[a][7]);
      }
    }
  }

  // Layer 3: per-atom dot with w3, reduce across the 32 channel groups.
  const float4 w3a = *(const float4*)(w3 + cA);
  const float4 w3b = *(const float4*)(w3 + cB);
  float part[4];
#pragma unroll
  for (int a = 0; a < 4; ++a) {
    part[a] = s[a][0] * w3a.x + s[a][1] * w3a.y + s[a][2] * w3a.z +
              s[a][3] * w3a.w + s[a][4] * w3b.x + s[a][5] * w3b.y +
              s[a][6] * w3b.z + s[a][7] * w3b.w;
  }
  __syncthreads();  // WK reads done; reuse as reduce buffer [32][33]
  float* red = WK;
#pragma unroll
  for (int a = 0; a < 4; ++a) red[(ta * 4 + a) * 33 + tc] = part[a];
  __syncthreads();
  if (tid < 32) {
    float sum = 0.f;
#pragma unroll
    for (int j = 0; j < 32; ++j) sum += red[tid * 33 + j];
    const int ga = a0 + tid;
    if (ga < natoms) out[ga] = sum + b3[0];
  }
}

extern "C" void kernel_launch(void* const* d_in, const int* in_sizes, int n_in,
                              void* d_out, int out_size, void* d_ws,
                              size_t ws_size, hipStream_t stream) {
  const float* x = (const float*)d_in[0];
  const float* rbf = (const float*)d_in[1];
  const int* eidx = (const int*)d_in[3];
  const float* w_rbf = (const float*)d_in[4];
  const float* b_rbf = (const float*)d_in[5];
  const float* w1 = (const float*)d_in[6];
  const float* b1 = (const float*)d_in[7];
  const float* w2 = (const float*)d_in[8];
  const float* b2 = (const float*)d_in[9];
  const float* w3 = (const float*)d_in[10];
  const float* b3 = (const float*)d_in[11];
  float* out = (float*)d_out;
  const int E = in_sizes[0] / CDIM;

  // Workspace layout.
  char* p = (char*)d_ws;
  float* acc = (float*)p;              p += (size_t)NATOMS * CDIM * sizeof(float);
  float* w1T = (float*)p;              p += CDIM * CDIM * sizeof(float);
  float* w2T = (float*)p;              p += CDIM * CDIM * sizeof(float);
  int* counts = (int*)p;               p += NATOMS * sizeof(int);
  int* offsets = (int*)p;              p += (NATOMS + 1) * sizeof(int);
  int* cursor = (int*)p;               p += NATOMS * sizeof(int);
  int* elist = (int*)p;                p += (size_t)E * sizeof(int);

  hipMemsetAsync(counts, 0, NATOMS * sizeof(int), stream);
  hist_kernel<<<(E + 255) / 256, 256, 0, stream>>>(eidx, counts, E);
  scan_kernel<<<1, 256, 0, stream>>>(counts, offsets, cursor);
  scatter_kernel<<<(E + 255) / 256, 256, 0, stream>>>(eidx, cursor, elist, E);
  transpose_kernel<<<dim3(8, 8, 2), dim3(32, 8), 0, stream>>>(w1, w2, w1T, w2T);
  gather_kernel<<<(NATOMS * 64 + 255) / 256, 256, 0, stream>>>(
      x, rbf, elist, offsets, w_rbf, b_rbf, acc);
  mlp_kernel<<<(NATOMS + 31) / 32, 256, 0, stream>>>(acc, w1T, b1, w2T, b2, w3,
                                                     b3, out, NATOMS);
}